// Round 1
// baseline (880.661 us; speedup 1.0000x reference)
//
#include <hip/hip_runtime.h>
#include <cstdint>
#include <cstddef>

#define C_DIM 768
#define N_DIM 16384

typedef __attribute__((ext_vector_type(8))) short short8;   // 8 bf16 = 4 VGPRs
typedef __attribute__((ext_vector_type(4))) float f32x4;

__device__ __forceinline__ ushort f2bf(float f) {
    uint32_t u = __float_as_uint(f);
    uint32_t r = 0x7fffu + ((u >> 16) & 1u);   // round-to-nearest-even
    return (ushort)((u + r) >> 16);
}

__device__ __forceinline__ void async_ld16(const void* g, void* l) {
    __builtin_amdgcn_global_load_lds(
        (__attribute__((address_space(1))) void*)g,
        (__attribute__((address_space(3))) void*)l,
        16, 0, 0);
}

// ---------------------------------------------------------------------------
// Normalize columns of F (C_DIM x N_DIM, row-major over C) and write the
// normalized values transposed as bf16: T[i][c] = F[c][i] / max(||col_i||,eps)
// Block: 256 threads, 64 columns per block.
// ---------------------------------------------------------------------------
__global__ __launch_bounds__(256) void norm_tr(const float* __restrict__ F,
                                               ushort* __restrict__ T) {
    const int i0 = blockIdx.x * 64;
    const int t  = threadIdx.x;
    const int tx = t & 63;        // column within tile
    const int ty = t >> 6;        // 0..3

    // ---- phase 1: per-column sum of squares ----
    float ss = 0.f;
    for (int c = ty; c < C_DIM; c += 4) {
        float v = F[(size_t)c * N_DIM + i0 + tx];
        ss += v * v;
    }
    __shared__ float red[4][64];
    __shared__ float scale[64];
    red[ty][tx] = ss;
    __syncthreads();
    if (t < 64) {
        float s = red[0][t] + red[1][t] + red[2][t] + red[3][t];
        float n = sqrtf(s);
        scale[t] = 1.0f / fmaxf(n, 1e-12f);
    }
    __syncthreads();

    // ---- phase 2: transpose in 64x64 chunks, scaled, write bf16 ----
    __shared__ float tile[64][65];   // +1 pad: conflict-free
    const int i_l   = t >> 3;        // 0..31
    const int c_off = (t & 7) * 8;   // 0..56
    for (int c0 = 0; c0 < C_DIM; c0 += 64) {
        #pragma unroll
        for (int rr = 0; rr < 16; ++rr) {
            int c_l = rr * 4 + ty;
            tile[c_l][tx] = F[(size_t)(c0 + c_l) * N_DIM + i0 + tx] * scale[tx];
        }
        __syncthreads();
        #pragma unroll
        for (int half = 0; half < 2; ++half) {
            int il = i_l + half * 32;
            __align__(16) ushort pack[8];
            #pragma unroll
            for (int j = 0; j < 8; ++j)
                pack[j] = f2bf(tile[c_off + j][il]);
            *(uint4*)&T[(size_t)(i0 + il) * C_DIM + c0 + c_off] = *(const uint4*)pack;
        }
        __syncthreads();
    }
}

// ---------------------------------------------------------------------------
// Fused GEMM + row-max:  sim[m][n] = dot(A[m][:], B[n][:]) over K=768 (bf16),
// per-row max over all n merged into rowkey[] via ordered-uint atomicMax.
// m97 structure: 128x128 tile, BK=32, 4 waves of 4x4 mfma_f32_16x16x32_bf16,
// global_load_lds width=16, 2-barrier K-loop.
// ---------------------------------------------------------------------------
__global__ __launch_bounds__(256) void gemm_rowmax(const ushort* __restrict__ A,
                                                   const ushort* __restrict__ B,
                                                   unsigned* __restrict__ rowkey) {
    __shared__ __align__(16) ushort As[128 * 32];
    __shared__ __align__(16) ushort Bs[128 * 32];

    const int t    = threadIdx.x;
    const int lane = t & 63;
    const int w    = t >> 6;
    const int wm   = w >> 1, wn = w & 1;
    const int m0   = blockIdx.y * 128;
    const int n0   = blockIdx.x * 128;

    f32x4 acc[4][4];
    #pragma unroll
    for (int i = 0; i < 4; ++i)
        #pragma unroll
        for (int j = 0; j < 4; ++j)
            acc[i][j] = (f32x4){0.f, 0.f, 0.f, 0.f};

    // staging: thread t loads 16B at row (t>>2), k-offset (t&3)*8; two issues
    // per operand cover 128 rows. LDS layout [row][k] = 64B rows -> dest
    // byte offset is exactly t*16 (wave-uniform base + lane*16). No padding
    // (global_load_lds requires it).
    const int r  = t >> 2;
    const int kq = (t & 3) * 8;
    const ushort* ag0 = A + (size_t)(m0 + r) * C_DIM + kq;
    const ushort* ag1 = ag0 + (size_t)64 * C_DIM;
    const ushort* bg0 = B + (size_t)(n0 + r) * C_DIM + kq;
    const ushort* bg1 = bg0 + (size_t)64 * C_DIM;
    ushort* asd0 = As + t * 8;
    ushort* asd1 = As + 64 * 32 + t * 8;
    ushort* bsd0 = Bs + t * 8;
    ushort* bsd1 = Bs + 64 * 32 + t * 8;

    // fragment read offsets (elements): A[m=lane&15][k=(lane>>4)*8+j]
    const int a_off = (wm * 64 + (lane & 15)) * 32 + (lane >> 4) * 8;
    const int b_off = (wn * 64 + (lane & 15)) * 32 + (lane >> 4) * 8;

    for (int k0 = 0; k0 < C_DIM; k0 += 32) {
        async_ld16(ag0 + k0, asd0);
        async_ld16(ag1 + k0, asd1);
        async_ld16(bg0 + k0, bsd0);
        async_ld16(bg1 + k0, bsd1);
        __syncthreads();   // compiler emits vmcnt(0) drain before barrier

        short8 af[4], bfr[4];
        #pragma unroll
        for (int mt = 0; mt < 4; ++mt)
            af[mt] = *(const short8*)(As + a_off + mt * 16 * 32);
        #pragma unroll
        for (int nt = 0; nt < 4; ++nt)
            bfr[nt] = *(const short8*)(Bs + b_off + nt * 16 * 32);
        #pragma unroll
        for (int mt = 0; mt < 4; ++mt)
            #pragma unroll
            for (int nt = 0; nt < 4; ++nt)
                acc[mt][nt] = __builtin_amdgcn_mfma_f32_16x16x32_bf16(
                    af[mt], bfr[nt], acc[mt][nt], 0, 0, 0);
        __syncthreads();
    }

    // epilogue: per-row max over this block's 128 columns.
    // C/D layout: col = lane&15, row = (lane>>4)*4 + reg.
    #pragma unroll
    for (int mt = 0; mt < 4; ++mt) {
        #pragma unroll
        for (int reg = 0; reg < 4; ++reg) {
            float v = fmaxf(fmaxf(acc[mt][0][reg], acc[mt][1][reg]),
                            fmaxf(acc[mt][2][reg], acc[mt][3][reg]));
            #pragma unroll
            for (int off = 1; off < 16; off <<= 1)
                v = fmaxf(v, __shfl_xor(v, off, 64));
            if ((lane & 15) == 0) {
                int m = m0 + wm * 64 + mt * 16 + (lane >> 4) * 4 + reg;
                unsigned u = __float_as_uint(v);
                u = (u & 0x80000000u) ? ~u : (u | 0x80000000u);  // order-preserving
                atomicMax(&rowkey[m], u);
            }
        }
    }
}

// ---------------------------------------------------------------------------
// Final: loss = 1 - mean(rowmax)
// ---------------------------------------------------------------------------
__global__ __launch_bounds__(256) void finalize(const unsigned* __restrict__ rowkey,
                                                float* __restrict__ out) {
    const int t = threadIdx.x;
    float s = 0.f;
    for (int i = t; i < N_DIM; i += 256) {
        unsigned u = rowkey[i];
        float f = (u & 0x80000000u) ? __uint_as_float(u ^ 0x80000000u)
                                    : __uint_as_float(~u);
        s += f;
    }
    #pragma unroll
    for (int off = 32; off >= 1; off >>= 1)
        s += __shfl_down(s, off, 64);
    __shared__ float part[4];
    if ((t & 63) == 0) part[t >> 6] = s;
    __syncthreads();
    if (t == 0)
        out[0] = 1.0f - (part[0] + part[1] + part[2] + part[3]) * (1.0f / (float)N_DIM);
}

extern "C" void kernel_launch(void* const* d_in, const int* in_sizes, int n_in,
                              void* d_out, int out_size, void* d_ws, size_t ws_size,
                              hipStream_t stream) {
    const float* F_r = (const float*)d_in[0];
    const float* F_s = (const float*)d_in[1];

    ushort*   Rt     = (ushort*)d_ws;                       // 16384 x 768 bf16
    ushort*   St     = Rt + (size_t)N_DIM * C_DIM;          // 16384 x 768 bf16
    unsigned* rowkey = (unsigned*)(St + (size_t)N_DIM * C_DIM);  // 16384 u32
    float*    out    = (float*)d_out;

    hipLaunchKernelGGL(norm_tr, dim3(N_DIM / 64), dim3(256), 0, stream, F_r, Rt);
    hipLaunchKernelGGL(norm_tr, dim3(N_DIM / 64), dim3(256), 0, stream, F_s, St);
    hipMemsetAsync(rowkey, 0, N_DIM * sizeof(unsigned), stream);
    hipLaunchKernelGGL(gemm_rowmax, dim3(N_DIM / 128, N_DIM / 128), dim3(256),
                       0, stream, Rt, St, rowkey);
    hipLaunchKernelGGL(finalize, dim3(1), dim3(256), 0, stream, rowkey, out);
}

// Round 2
// 787.389 us; speedup vs baseline: 1.1185x; 1.1185x over previous
//
#include <hip/hip_runtime.h>
#include <cstdint>
#include <cstddef>

#define C_DIM 768
#define N_DIM 16384

typedef __attribute__((ext_vector_type(8))) short short8;   // 8 bf16 = 4 VGPRs
typedef __attribute__((ext_vector_type(4))) float f32x4;

__device__ __forceinline__ ushort f2bf(float f) {
    uint32_t u = __float_as_uint(f);
    uint32_t r = 0x7fffu + ((u >> 16) & 1u);   // round-to-nearest-even
    return (ushort)((u + r) >> 16);
}

__device__ __forceinline__ void async_ld16(const void* g, void* l) {
    __builtin_amdgcn_global_load_lds(
        (__attribute__((address_space(1))) void*)g,
        (__attribute__((address_space(3))) void*)l,
        16, 0, 0);
}

// ---------------------------------------------------------------------------
// Normalize columns of F (C_DIM x N_DIM) and write transposed bf16:
// T[i][c] = F[c][i] / max(||col_i||, eps).  blockIdx.y selects the input.
// ---------------------------------------------------------------------------
__global__ __launch_bounds__(256) void norm_tr(const float* __restrict__ F0,
                                               ushort* __restrict__ T0,
                                               const float* __restrict__ F1,
                                               ushort* __restrict__ T1) {
    const float*  F = blockIdx.y ? F1 : F0;
    ushort*       T = blockIdx.y ? T1 : T0;
    const int i0 = blockIdx.x * 64;
    const int t  = threadIdx.x;
    const int tx = t & 63;        // column within tile
    const int ty = t >> 6;        // 0..3

    // ---- phase 1: per-column sum of squares ----
    float ss = 0.f;
    for (int c = ty; c < C_DIM; c += 4) {
        float v = F[(size_t)c * N_DIM + i0 + tx];
        ss += v * v;
    }
    __shared__ float red[4][64];
    __shared__ float scale[64];
    red[ty][tx] = ss;
    __syncthreads();
    if (t < 64) {
        float s = red[0][t] + red[1][t] + red[2][t] + red[3][t];
        float n = sqrtf(s);
        scale[t] = 1.0f / fmaxf(n, 1e-12f);
    }
    __syncthreads();

    // ---- phase 2: transpose in 64x64 chunks, scaled, write bf16 ----
    __shared__ float tile[64][65];   // +1 pad: conflict-free
    const int i_l   = t >> 3;        // 0..31
    const int c_off = (t & 7) * 8;   // 0..56
    for (int c0 = 0; c0 < C_DIM; c0 += 64) {
        #pragma unroll
        for (int rr = 0; rr < 16; ++rr) {
            int c_l = rr * 4 + ty;
            tile[c_l][tx] = F[(size_t)(c0 + c_l) * N_DIM + i0 + tx] * scale[tx];
        }
        __syncthreads();
        #pragma unroll
        for (int half = 0; half < 2; ++half) {
            int il = i_l + half * 32;
            __align__(16) ushort pack[8];
            #pragma unroll
            for (int j = 0; j < 8; ++j)
                pack[j] = f2bf(tile[c_off + j][il]);
            *(uint4*)&T[(size_t)(i0 + il) * C_DIM + c0 + c_off] = *(const uint4*)pack;
        }
        __syncthreads();
    }
}

// ---------------------------------------------------------------------------
// Fused GEMM + row-max over K=768 bf16, m97 structure (128x128 tile, BK=32,
// 4 waves x 4x4 mfma_f32_16x16x32_bf16, global_load_lds width=16).
//
// LDS bank-conflict swizzle: thread t stages its 16B chunk at LDS byte t*16
// (required: global_load_lds dest = uniform base + lane*16), but sources the
// LOGICAL k-quad  kl = (t&3) ^ ((t>>3)&3)  from global.  Fragment reads then
// find logical k-quad x at quadpos  x ^ ((row>>1)&3):
//   bank-quad(lane) = 4*(row&1) + quadpos -> lanes 0..7 cover all 8 quads,
//   2 lanes/quad over the wave = 2-way = free (m136).  Without the swizzle
//   the quad index is constant per 16-lane group -> 8-way conflict (~2.9x),
//   which was the round-1 bottleneck (SQ_LDS_BANK_CONFLICT = 5e7).
// ---------------------------------------------------------------------------
__global__ __launch_bounds__(256) void gemm_rowmax(const ushort* __restrict__ A,
                                                   const ushort* __restrict__ B,
                                                   unsigned* __restrict__ rowkey) {
    __shared__ __align__(16) ushort As[128 * 32];
    __shared__ __align__(16) ushort Bs[128 * 32];

    const int t    = threadIdx.x;
    const int lane = t & 63;
    const int w    = t >> 6;
    const int wm   = w >> 1, wn = w & 1;
    const int m0   = blockIdx.y * 128;
    const int n0   = blockIdx.x * 128;

    f32x4 acc[4][4];
    #pragma unroll
    for (int i = 0; i < 4; ++i)
        #pragma unroll
        for (int j = 0; j < 4; ++j)
            acc[i][j] = (f32x4){0.f, 0.f, 0.f, 0.f};

    // staging: thread t -> row r = t>>2 (and r+64), LDS byte offset t*16.
    // logical k-quad sourced from global is XOR-swizzled by row bits 1-2.
    const int r  = t >> 2;
    const int kl = (t & 3) ^ ((t >> 3) & 3);   // (t>>3)&3 == (r>>1)&3
    const int kq = kl * 8;
    const ushort* ag0 = A + (size_t)(m0 + r) * C_DIM + kq;
    const ushort* ag1 = ag0 + (size_t)64 * C_DIM;   // row bits 1-2 unchanged
    const ushort* bg0 = B + (size_t)(n0 + r) * C_DIM + kq;
    const ushort* bg1 = bg0 + (size_t)64 * C_DIM;
    ushort* asd0 = As + t * 8;
    ushort* asd1 = As + 64 * 32 + t * 8;
    ushort* bsd0 = Bs + t * 8;
    ushort* bsd1 = Bs + 64 * 32 + t * 8;

    // fragment read offsets (elements): logical k-quad x = lane>>4 lives at
    // quadpos x ^ ((row>>1)&3); row = base + (lane&15), base % 16 == 0.
    const int qp    = ((lane >> 4) ^ ((lane >> 1) & 3)) * 8;
    const int a_off = (wm * 64 + (lane & 15)) * 32 + qp;
    const int b_off = (wn * 64 + (lane & 15)) * 32 + qp;

    for (int k0 = 0; k0 < C_DIM; k0 += 32) {
        async_ld16(ag0 + k0, asd0);
        async_ld16(ag1 + k0, asd1);
        async_ld16(bg0 + k0, bsd0);
        async_ld16(bg1 + k0, bsd1);
        __syncthreads();

        short8 af[4], bfr[4];
        #pragma unroll
        for (int mt = 0; mt < 4; ++mt)
            af[mt] = *(const short8*)(As + a_off + mt * 16 * 32);
        #pragma unroll
        for (int nt = 0; nt < 4; ++nt)
            bfr[nt] = *(const short8*)(Bs + b_off + nt * 16 * 32);
        #pragma unroll
        for (int mt = 0; mt < 4; ++mt)
            #pragma unroll
            for (int nt = 0; nt < 4; ++nt)
                acc[mt][nt] = __builtin_amdgcn_mfma_f32_16x16x32_bf16(
                    af[mt], bfr[nt], acc[mt][nt], 0, 0, 0);
        __syncthreads();
    }

    // epilogue: per-row max over this block's 128 columns.
    // C/D layout: col = lane&15, row = (lane>>4)*4 + reg.
    #pragma unroll
    for (int mt = 0; mt < 4; ++mt) {
        #pragma unroll
        for (int reg = 0; reg < 4; ++reg) {
            float v = fmaxf(fmaxf(acc[mt][0][reg], acc[mt][1][reg]),
                            fmaxf(acc[mt][2][reg], acc[mt][3][reg]));
            #pragma unroll
            for (int off = 1; off < 16; off <<= 1)
                v = fmaxf(v, __shfl_xor(v, off, 64));
            if ((lane & 15) == 0) {
                int m = m0 + wm * 64 + mt * 16 + (lane >> 4) * 4 + reg;
                unsigned u = __float_as_uint(v);
                u = (u & 0x80000000u) ? ~u : (u | 0x80000000u);  // order-preserving
                atomicMax(&rowkey[m], u);
            }
        }
    }
}

// ---------------------------------------------------------------------------
// Final: loss = 1 - mean(rowmax)
// ---------------------------------------------------------------------------
__global__ __launch_bounds__(1024) void finalize(const unsigned* __restrict__ rowkey,
                                                 float* __restrict__ out) {
    const int t = threadIdx.x;
    float s = 0.f;
    for (int i = t; i < N_DIM; i += 1024) {
        unsigned u = rowkey[i];
        float f = (u & 0x80000000u) ? __uint_as_float(u ^ 0x80000000u)
                                    : __uint_as_float(~u);
        s += f;
    }
    #pragma unroll
    for (int off = 32; off >= 1; off >>= 1)
        s += __shfl_down(s, off, 64);
    __shared__ float part[16];
    if ((t & 63) == 0) part[t >> 6] = s;
    __syncthreads();
    if (t == 0) {
        float tot = 0.f;
        #pragma unroll
        for (int i = 0; i < 16; ++i) tot += part[i];
        out[0] = 1.0f - tot * (1.0f / (float)N_DIM);
    }
}

extern "C" void kernel_launch(void* const* d_in, const int* in_sizes, int n_in,
                              void* d_out, int out_size, void* d_ws, size_t ws_size,
                              hipStream_t stream) {
    const float* F_r = (const float*)d_in[0];
    const float* F_s = (const float*)d_in[1];

    ushort*   Rt     = (ushort*)d_ws;                       // 16384 x 768 bf16
    ushort*   St     = Rt + (size_t)N_DIM * C_DIM;          // 16384 x 768 bf16
    unsigned* rowkey = (unsigned*)(St + (size_t)N_DIM * C_DIM);  // 16384 u32
    float*    out    = (float*)d_out;

    hipLaunchKernelGGL(norm_tr, dim3(N_DIM / 64, 2), dim3(256), 0, stream,
                       F_r, Rt, F_s, St);
    hipMemsetAsync(rowkey, 0, N_DIM * sizeof(unsigned), stream);
    hipLaunchKernelGGL(gemm_rowmax, dim3(N_DIM / 128, N_DIM / 128), dim3(256),
                       0, stream, Rt, St, rowkey);
    hipLaunchKernelGGL(finalize, dim3(1), dim3(1024), 0, stream, rowkey, out);
}